// Round 1
// 269.422 us; speedup vs baseline: 1.1203x; 1.1203x over previous
//
#include <hip/hip_runtime.h>
#include <hip/hip_bf16.h>

#define SEQ 2048
#define DMODEL 2048
#define NHEAD 8
#define DHEAD 256

typedef _Float16 v8h __attribute__((ext_vector_type(8)));
typedef unsigned short v8u __attribute__((ext_vector_type(8)));
typedef float v4f __attribute__((ext_vector_type(4)));

__device__ __forceinline__ float b2f(unsigned short s) {
    return __uint_as_float(((unsigned)s) << 16);
}
__device__ __forceinline__ unsigned short f2b(float f) {
    unsigned u = __float_as_uint(f);
    u += 0x7fffu + ((u >> 16) & 1u);   // RNE
    return (unsigned short)(u >> 16);
}
__device__ __forceinline__ unsigned short f2h(float f) {
    _Float16 h = (_Float16)f;
    return __builtin_bit_cast(unsigned short, h);
}
__device__ __forceinline__ float h2f(unsigned short s) {
    return (float)__builtin_bit_cast(_Float16, s);
}

// ---------------------------------------------------------------- detect dtype
__global__ __launch_bounds__(256) void k_detect(const unsigned short* q, int* flag) {
    __shared__ int cnt;
    if (threadIdx.x == 0) cnt = 0;
    __syncthreads();
    int wild = 0;
    for (int i = threadIdx.x; i < 2048; i += 256) {
        float x = b2f(q[i]);
        float ax = fabsf(x);
        if (!(ax <= 100.0f) || (x != 0.0f && ax < 1e-6f)) wild++;
    }
    atomicAdd(&cnt, wild);
    __syncthreads();
    if (threadIdx.x == 0) *flag = (cnt < 256) ? 1 : 0;  // 1 = bf16, 0 = f32
}

// ----------------------------------------------- convert q, k -> fp16
__global__ __launch_bounds__(256) void k_cvt_qk(const void* q, const void* k,
                                                const int* flag,
                                                unsigned short* qb, unsigned short* kb) {
    int bf = *(volatile const int*)flag;
    size_t i0 = ((size_t)blockIdx.x * 256 + threadIdx.x) * 8;
    v8u oq, ok;
    if (bf) {
        v8u uq = *(const v8u*)((const unsigned short*)q + i0);
        v8u uk = *(const v8u*)((const unsigned short*)k + i0);
#pragma unroll
        for (int j = 0; j < 8; j++) {
            oq[j] = f2h(b2f(uq[j]));
            ok[j] = f2h(b2f(uk[j]));
        }
    } else {
        const float* qf = (const float*)q;
        const float* kf = (const float*)k;
#pragma unroll
        for (int j = 0; j < 8; j++) {
            oq[j] = f2h(qf[i0 + j]);
            ok[j] = f2h(kf[i0 + j]);
        }
    }
    *(v8u*)(qb + i0) = oq;
    *(v8u*)(kb + i0) = ok;
}

// ----------------------------------------------------------- out_weight -> f32
__global__ __launch_bounds__(256) void k_cvt_gw(const void* ow, const int* flag, float* gw) {
    int bf = *(volatile const int*)flag;
    int i = blockIdx.x * 256 + threadIdx.x;
    gw[i] = bf ? b2f(((const unsigned short*)ow)[i]) : ((const float*)ow)[i];
}

// ------------------------------------------- v -> vT[h][d][s] fp16 (transposed)
__global__ __launch_bounds__(256) void k_tr_v(const void* v, const int* flag,
                                              unsigned short* vT) {
    __shared__ unsigned short tile[64][72];
    int bf = *(volatile const int*)flag;
    int s0 = blockIdx.x * 64, d0 = blockIdx.y * 64;
    int r = threadIdx.x >> 2, c0 = (threadIdx.x & 3) * 16;
    size_t base = (size_t)(s0 + r) * DMODEL + d0 + c0;
    if (bf) {
        const unsigned short* vp = (const unsigned short*)v;
        v8u a = *(const v8u*)(vp + base);
        v8u b = *(const v8u*)(vp + base + 8);
#pragma unroll
        for (int j = 0; j < 8; j++) { tile[r][c0 + j] = f2h(b2f(a[j])); tile[r][c0 + 8 + j] = f2h(b2f(b[j])); }
    } else {
        const float* vp = (const float*)v;
#pragma unroll
        for (int j = 0; j < 16; j++) tile[r][c0 + j] = f2h(vp[base + j]);
    }
    __syncthreads();
    int dr = threadIdx.x >> 2, sc0 = (threadIdx.x & 3) * 16;
    v8u o0, o1;
#pragma unroll
    for (int j = 0; j < 8; j++) { o0[j] = tile[sc0 + j][dr]; o1[j] = tile[sc0 + 8 + j][dr]; }
    int head = d0 >> 8;
    int dh = (d0 & 255) + dr;
    size_t ob = ((size_t)head * DHEAD + dh) * SEQ + s0 + sc0;
    *(v8u*)(vT + ob) = o0;
    *(v8u*)(vT + ob + 8) = o1;
}

// --------------------------------------------- gate pre-activations (f32, no bias)
__global__ __launch_bounds__(256) void k_gates(const void* q, const void* k, const void* v,
                                               const void* igk, const void* fgk,
                                               const int* flag, float* ipre, float* fpre) {
    __shared__ float x_lds[32][68];
    int bf = *(volatile const int*)flag;
    int s0 = blockIdx.x * 32;
    int c  = blockIdx.y;
    int tid = threadIdx.x;
    int sl = tid >> 3, hh = tid & 7;
    int rr = tid >> 3, j0 = (tid & 7) * 8;
    float accI = 0.f, accF = 0.f;
    for (int wd = 0; wd < 12; ++wd) {
        int gd0 = c * 768 + wd * 64;
        const void* src; int off;
        if (gd0 < 2048)      { src = q; off = gd0; }
        else if (gd0 < 4096) { src = k; off = gd0 - 2048; }
        else                 { src = v; off = gd0 - 4096; }
        __syncthreads();
        size_t base = (size_t)(s0 + rr) * DMODEL + off + j0;
        if (bf) {
            const unsigned short* sp = (const unsigned short*)src;
            v8u a = *(const v8u*)(sp + base);
#pragma unroll
            for (int j = 0; j < 8; j++) x_lds[rr][j0 + j] = b2f(a[j]);
        } else {
            const float* sp = (const float*)src;
#pragma unroll
            for (int j = 0; j < 8; j++) x_lds[rr][j0 + j] = sp[base + j];
        }
        __syncthreads();
        if (bf) {
            const unsigned short* ik = (const unsigned short*)igk;
            const unsigned short* fk = (const unsigned short*)fgk;
#pragma unroll 8
            for (int j = 0; j < 64; j++) {
                float x = x_lds[sl][j];
                int wi = (gd0 + j) * NHEAD + hh;
                accI += x * b2f(ik[wi]);
                accF += x * b2f(fk[wi]);
            }
        } else {
            const float* ik = (const float*)igk;
            const float* fk = (const float*)fgk;
#pragma unroll 8
            for (int j = 0; j < 64; j++) {
                float x = x_lds[sl][j];
                int wi = (gd0 + j) * NHEAD + hh;
                accI += x * ik[wi];
                accF += x * fk[wi];
            }
        }
    }
    atomicAdd(&ipre[hh * SEQ + s0 + sl], accI);
    atomicAdd(&fpre[hh * SEQ + s0 + sl], accF);
}

// ---------------- per-head scans: cum(log_sigmoid(f)), a = i - cum, prefix-max
__global__ __launch_bounds__(256) void k_scan(const float* ipre, const float* fpre,
                                              const void* ib_, const void* fb_,
                                              const int* flag,
                                              float* a_g, float* amax_g, float* nfl_g) {
    __shared__ float sarr[256];
    int bf = *(volatile const int*)flag;
    int h = blockIdx.x, tid = threadIdx.x;
    float ib = bf ? b2f(((const unsigned short*)ib_)[h]) : ((const float*)ib_)[h];
    float fb = bf ? b2f(((const unsigned short*)fb_)[h]) : ((const float*)fb_)[h];
    int s0 = tid * 8;
    float lf[8], ip[8];
#pragma unroll
    for (int j = 0; j < 8; j++) {
        float fp = fpre[h * SEQ + s0 + j] + fb;
        lf[j] = fminf(fp, 0.0f) - log1pf(__expf(-fabsf(fp)));
        ip[j] = ipre[h * SEQ + s0 + j] + ib;
    }
    float cs[8]; float t = 0.f;
#pragma unroll
    for (int j = 0; j < 8; j++) { t += lf[j]; cs[j] = t; }
    sarr[tid] = t; __syncthreads();
    for (int ofs = 1; ofs < 256; ofs <<= 1) {
        float val = sarr[tid];
        if (tid >= ofs) val += sarr[tid - ofs];
        __syncthreads(); sarr[tid] = val; __syncthreads();
    }
    float excl = (tid > 0) ? sarr[tid - 1] : 0.0f;
    float cum[8], av[8];
#pragma unroll
    for (int j = 0; j < 8; j++) { cum[j] = excl + cs[j]; av[j] = ip[j] - cum[j]; }
    float mx = av[0];
#pragma unroll
    for (int j = 1; j < 8; j++) mx = fmaxf(mx, av[j]);
    __syncthreads(); sarr[tid] = mx; __syncthreads();
    for (int ofs = 1; ofs < 256; ofs <<= 1) {
        float val = sarr[tid];
        if (tid >= ofs) val = fmaxf(val, sarr[tid - ofs]);
        __syncthreads(); sarr[tid] = val; __syncthreads();
    }
    float run = (tid > 0) ? sarr[tid - 1] : -3.0e38f;
#pragma unroll
    for (int j = 0; j < 8; j++) {
        run = fmaxf(run, av[j]);
        int s = s0 + j;
        a_g[h * SEQ + s]    = av[j];
        amax_g[h * SEQ + s] = run;
        float m = cum[j] + run;
        nfl_g[h * SEQ + s]  = __expf(fminf(fmaxf(-m, -60.f), 60.f));
    }
}

// --------------------------------------------------------------- main kernel
// Equal-work blocks: each of 64 blocks/head processes a fixed quota (33/32,
// interleaved so any adjacent pair sums to 65) of flattened (tile, js) units.
// The js-sum is order-independent (precomputed amax), so split tiles combine
// via f32 atomicAdd into h_buf/rs_buf; k_finish applies normalizer + LN.
__global__ __launch_bounds__(256) void k_main(const unsigned short* __restrict__ qb,
                                              const unsigned short* __restrict__ kb,
                                              const unsigned short* __restrict__ vT,
                                              const float* __restrict__ a_g,
                                              const float* __restrict__ amax_g,
                                              float* __restrict__ h_buf,
                                              float* __restrict__ rs_buf) {
    __shared__ __align__(16) unsigned short q_lds[32][264];
    __shared__ __align__(16) unsigned short k_lds[32][264];
    __shared__ __align__(16) unsigned short vT_lds[272][40];   // rows 256..271: ones/zeros
    __shared__ __align__(16) unsigned short P_lds[32][40];
    __shared__ __align__(16) unsigned short Plo_lds[32][40];
    __shared__ float a_s[32], amax_t[32];

    const int h   = blockIdx.x;
    const int y   = blockIdx.y;        // quota index within head, 0..63
    const int tid = threadIdx.x;
    const int lane = tid & 63;
    const int w   = tid >> 6;          // wave 0..3
    const int l15 = lane & 15;
    const int qd  = (lane >> 4) & 3;   // quad
    const int hd0 = h * DHEAD;

    // ---- quota: units [u, u+remaining) of this head's flattened triangle
    int u         = 65 * (y >> 1) + ((y & 1) ? 33 : 0);
    int remaining = (y & 1) ? 32 : 33;
    int tile = (int)((sqrtf(8.0f * (float)u + 1.0f) - 1.0f) * 0.5f);
    while ((tile + 1) * (tile + 2) / 2 <= u) ++tile;
    while (tile * (tile + 1) / 2 > u) --tile;
    int js = u - tile * (tile + 1) / 2;
    bool needQ = true;

    // ones/zeros rows for the normalizer trick
    for (int i = tid; i < 16 * 40; i += 256) {
        int r2 = i / 40, c2 = i % 40;
        vT_lds[256 + r2][c2] = (r2 == 0 && c2 < 32) ? (unsigned short)0x3C00 : (unsigned short)0;
    }

    const v4f vzero = {0.f, 0.f, 0.f, 0.f};
    v4f acc[2][4];
    v4f accN[2];
#pragma unroll
    for (int m = 0; m < 2; m++) {
        accN[m] = vzero;
#pragma unroll
        for (int n = 0; n < 4; n++) acc[m][n] = vzero;
    }

    const int mw = w >> 1, nw = w & 1;
    const int krow = tid >> 3, kc0 = (tid & 7) * 32;

    // staging registers (async-split: load early, ds_write late)
    v8u kr0, kr1, kr2, kr3, vr0, vr1, vr2, vr3;
    float areg = 0.f;
    {   // prefetch first unit
        const int s0 = js * 32;
        const unsigned short* ks = kb + (size_t)(s0 + krow) * DMODEL + hd0 + kc0;
        kr0 = *(const v8u*)(ks);      kr1 = *(const v8u*)(ks + 8);
        kr2 = *(const v8u*)(ks + 16); kr3 = *(const v8u*)(ks + 24);
        const unsigned short* vs = vT + (size_t)(hd0 + tid) * SEQ + s0;
        vr0 = *(const v8u*)(vs);      vr1 = *(const v8u*)(vs + 8);
        vr2 = *(const v8u*)(vs + 16); vr3 = *(const v8u*)(vs + 24);
        if (tid < 32) areg = a_g[h * SEQ + s0 + tid];
    }

    for (;;) {
        const int t0 = tile * 32;
        __syncthreads();   // previous unit's compute consumed LDS
        if (needQ) {       // new tile: stage q + per-row stabilizer
            const unsigned short* src = qb + (size_t)(t0 + krow) * DMODEL + hd0 + kc0;
#pragma unroll
            for (int i = 0; i < 4; i++)
                *(v8u*)&q_lds[krow][kc0 + i * 8] = *(const v8u*)(src + i * 8);
            if (tid < 32) amax_t[tid] = amax_g[h * SEQ + t0 + tid];
            needQ = false;
        }
        *(v8u*)&k_lds[krow][kc0]      = kr0;
        *(v8u*)&k_lds[krow][kc0 + 8]  = kr1;
        *(v8u*)&k_lds[krow][kc0 + 16] = kr2;
        *(v8u*)&k_lds[krow][kc0 + 24] = kr3;
        *(v8u*)&vT_lds[tid][0]  = vr0;
        *(v8u*)&vT_lds[tid][8]  = vr1;
        *(v8u*)&vT_lds[tid][16] = vr2;
        *(v8u*)&vT_lds[tid][24] = vr3;
        if (tid < 32) a_s[tid] = areg;
        __syncthreads();

        // QK^T: each wave computes one 16x16 tile of P (mw,nw)
        v4f c = vzero;
#pragma unroll
        for (int d0 = 0; d0 < 256; d0 += 32) {
            v8h a = *(const v8h*)&q_lds[mw * 16 + l15][d0 + qd * 8];
            v8h b = *(const v8h*)&k_lds[nw * 16 + l15][d0 + qd * 8];
            c = __builtin_amdgcn_mfma_f32_16x16x32_f16(a, b, c, 0, 0, 0);
        }
        // decay weights + causal mask; write P as fp16 hi + lo residual
        {
            const bool diag = (js == tile);
            const int col = nw * 16 + l15;
            const float av = a_s[col];
#pragma unroll
            for (int r = 0; r < 4; r++) {
                int row = mw * 16 + qd * 4 + r;
                float arg = fminf(av - amax_t[row], 0.0f);
                float val = c[r] * 0.0625f * __expf(arg);   // 1/sqrt(256) folded here
                if (diag && col > row) val = 0.0f;
                unsigned short hi = f2h(val);
                float lo = val - h2f(hi);
                P_lds[row][col]   = hi;
                Plo_lds[row][col] = f2h(lo);
            }
        }
        __syncthreads();

        // prefetch NEXT unit now; HBM/L2 latency hides under the PV phase below
        int ntile = tile, njs = js + 1; bool nq = false;
        if (njs > tile) { ntile = tile + 1; njs = 0; nq = true; }
        if (remaining > 1) {
            const int s0 = njs * 32;
            const unsigned short* ks = kb + (size_t)(s0 + krow) * DMODEL + hd0 + kc0;
            kr0 = *(const v8u*)(ks);      kr1 = *(const v8u*)(ks + 8);
            kr2 = *(const v8u*)(ks + 16); kr3 = *(const v8u*)(ks + 24);
            const unsigned short* vs = vT + (size_t)(hd0 + tid) * SEQ + s0;
            vr0 = *(const v8u*)(vs);      vr1 = *(const v8u*)(vs + 8);
            vr2 = *(const v8u*)(vs + 16); vr3 = *(const v8u*)(vs + 24);
            if (tid < 32) areg = a_g[h * SEQ + s0 + tid];
        }

        // P @ V (hi + lo): wave w owns output cols [w*64, w*64+64)
        v8h aH0 = *(const v8h*)&P_lds[l15][qd * 8];
        v8h aH1 = *(const v8h*)&P_lds[16 + l15][qd * 8];
        v8h aL0 = *(const v8h*)&Plo_lds[l15][qd * 8];
        v8h aL1 = *(const v8h*)&Plo_lds[16 + l15][qd * 8];
#pragma unroll
        for (int nn = 0; nn < 4; nn++) {
            v8h bV = *(const v8h*)&vT_lds[w * 64 + nn * 16 + l15][qd * 8];
            acc[0][nn] = __builtin_amdgcn_mfma_f32_16x16x32_f16(aH0, bV, acc[0][nn], 0, 0, 0);
            acc[0][nn] = __builtin_amdgcn_mfma_f32_16x16x32_f16(aL0, bV, acc[0][nn], 0, 0, 0);
            acc[1][nn] = __builtin_amdgcn_mfma_f32_16x16x32_f16(aH1, bV, acc[1][nn], 0, 0, 0);
            acc[1][nn] = __builtin_amdgcn_mfma_f32_16x16x32_f16(aL1, bV, acc[1][nn], 0, 0, 0);
        }
        if (w == 3) {   // ones-column trick: row normalizer (hi+lo)
            v8h bN = *(const v8h*)&vT_lds[256 + l15][qd * 8];
            accN[0] = __builtin_amdgcn_mfma_f32_16x16x32_f16(aH0, bN, accN[0], 0, 0, 0);
            accN[0] = __builtin_amdgcn_mfma_f32_16x16x32_f16(aL0, bN, accN[0], 0, 0, 0);
            accN[1] = __builtin_amdgcn_mfma_f32_16x16x32_f16(aH1, bN, accN[1], 0, 0, 0);
            accN[1] = __builtin_amdgcn_mfma_f32_16x16x32_f16(aL1, bN, accN[1], 0, 0, 0);
        }

        // flush at tile end or block end (raw partials; fire-and-forget atomics)
        if (js == tile || remaining == 1) {
#pragma unroll
            for (int m = 0; m < 2; m++)
#pragma unroll
                for (int r = 0; r < 4; r++) {
                    int row = t0 + m * 16 + qd * 4 + r;
#pragma unroll
                    for (int nn = 0; nn < 4; nn++) {
                        int col = hd0 + w * 64 + nn * 16 + l15;
                        atomicAdd(&h_buf[(size_t)row * DMODEL + col], acc[m][nn][r]);
                        acc[m][nn][r] = 0.f;
                    }
                    if (w == 3 && l15 == 0)
                        atomicAdd(&rs_buf[h * SEQ + row], accN[m][r]);
                    accN[m][r] = 0.f;
                }
        }
        if (--remaining == 0) break;
        tile = ntile; js = njs; needQ = nq;
    }
}

// ------------------------------------- finish: normalizer scale + per-head LN
__global__ __launch_bounds__(256) void k_finish(const float* __restrict__ h_buf,
                                                const float* __restrict__ rs_buf,
                                                const float* __restrict__ nfl_g,
                                                const float* __restrict__ gw,
                                                const int* flag, void* out) {
    const int wv = threadIdx.x >> 6, lane = threadIdx.x & 63;
    const int rid = blockIdx.x * 4 + wv;       // 0..16383
    const int s = rid >> 3, h = rid & 7;
    const int bf = *(volatile const int*)flag;
    float rs  = rs_buf[h * SEQ + s];
    float nfl = nfl_g[h * SEQ + s];
    float sc  = 1.0f / (fmaxf(fabsf(rs), nfl) + 1e-6f);
    size_t base = (size_t)s * DMODEL + h * DHEAD + lane * 4;
    v4f hv = *(const v4f*)(h_buf + base);
#pragma unroll
    for (int j = 0; j < 4; j++) hv[j] *= sc;
    float sm = hv[0] + hv[1] + hv[2] + hv[3];
    float sq = hv[0] * hv[0] + hv[1] * hv[1] + hv[2] * hv[2] + hv[3] * hv[3];
#pragma unroll
    for (int m = 1; m < 64; m <<= 1) {
        sm += __shfl_xor(sm, m, 64);
        sq += __shfl_xor(sq, m, 64);
    }
    float mean = sm * (1.0f / 256.0f);
    float var  = fmaxf(sq * (1.0f / 256.0f) - mean * mean, 0.0f);
    float rstd = rsqrtf(var + 1e-6f);
    const float* g = gw + h * DHEAD + lane * 4;
    if (bf) {
        unsigned short* o = (unsigned short*)out + base;
#pragma unroll
        for (int j = 0; j < 4; j++) o[j] = f2b((hv[j] - mean) * rstd * g[j]);
    } else {
        float* o = (float*)out + base;
#pragma unroll
        for (int j = 0; j < 4; j++) o[j] = (hv[j] - mean) * rstd * g[j];
    }
}

// ---------------------------------------------------------------------- host
extern "C" void kernel_launch(void* const* d_in, const int* in_sizes, int n_in,
                              void* d_out, int out_size, void* d_ws, size_t ws_size,
                              hipStream_t stream) {
    const void* q   = d_in[0];
    const void* k   = d_in[1];
    const void* v   = d_in[2];
    const void* igk = d_in[3];
    const void* igb = d_in[4];
    const void* fgk = d_in[5];
    const void* fgb = d_in[6];
    const void* ow  = d_in[7];

    char* ws = (char*)d_ws;
    int*   flag   = (int*)(ws + 0);
    float* ipre   = (float*)(ws + 1024);
    float* fpre   = (float*)(ws + 1024 + 1 * 65536);
    float* a_g    = (float*)(ws + 1024 + 2 * 65536);
    float* amax_g = (float*)(ws + 1024 + 3 * 65536);
    float* nfl_g  = (float*)(ws + 1024 + 4 * 65536);
    float* gw     = (float*)(ws + 1024 + 5 * 65536);
    unsigned short* qb = (unsigned short*)(ws + 1024 + 5 * 65536 + 8192);
    unsigned short* kb = qb + (size_t)SEQ * DMODEL;
    unsigned short* vT = kb + (size_t)SEQ * DMODEL;
    float* rs_buf = (float*)((char*)vT + (size_t)SEQ * DMODEL * 2);
    float* h_buf  = (float*)((char*)rs_buf + 65536);

    hipMemsetAsync(ipre, 0, 2 * 65536, stream);
    hipMemsetAsync(rs_buf, 0, 65536 + (size_t)SEQ * DMODEL * 4, stream);  // rs + h contiguous
    k_detect<<<1, 256, 0, stream>>>((const unsigned short*)q, flag);
    k_cvt_qk<<<2048, 256, 0, stream>>>(q, k, flag, qb, kb);
    k_cvt_gw<<<8, 256, 0, stream>>>(ow, flag, gw);
    k_tr_v<<<dim3(32, 32), 256, 0, stream>>>(v, flag, vT);
    k_gates<<<dim3(64, 8), 256, 0, stream>>>(q, k, v, igk, fgk, flag, ipre, fpre);
    k_scan<<<8, 256, 0, stream>>>(ipre, fpre, igb, fgb, flag, a_g, amax_g, nfl_g);
    k_main<<<dim3(8, 64), 256, 0, stream>>>(qb, kb, vT, a_g, amax_g, h_buf, rs_buf);
    k_finish<<<4096, 256, 0, stream>>>(h_buf, rs_buf, nfl_g, gw, flag, d_out);
}

// Round 2
// 268.222 us; speedup vs baseline: 1.1253x; 1.0045x over previous
//
#include <hip/hip_runtime.h>
#include <hip/hip_bf16.h>

#define SEQ 2048
#define DMODEL 2048
#define NHEAD 8
#define DHEAD 256

typedef _Float16 v8h __attribute__((ext_vector_type(8)));
typedef unsigned short v8u __attribute__((ext_vector_type(8)));
typedef float v4f __attribute__((ext_vector_type(4)));

__device__ __forceinline__ float b2f(unsigned short s) {
    return __uint_as_float(((unsigned)s) << 16);
}
__device__ __forceinline__ unsigned short f2b(float f) {
    unsigned u = __float_as_uint(f);
    u += 0x7fffu + ((u >> 16) & 1u);   // RNE
    return (unsigned short)(u >> 16);
}
__device__ __forceinline__ unsigned short f2h(float f) {
    _Float16 h = (_Float16)f;
    return __builtin_bit_cast(unsigned short, h);
}
__device__ __forceinline__ float h2f(unsigned short s) {
    return (float)__builtin_bit_cast(_Float16, s);
}

// --------------------------------------------------------------- fused pre
// grid (64 s-stripes, 6): z = {0,1}: q halves, {2,3}: k halves, {4,5}: v halves.
// One read of q/k/v serves: fp16 convert (q,k), transpose (v), gate partials.
// Dtype detect is recomputed per block (deterministic) -> no detect kernel.
__global__ __launch_bounds__(256) void k_pre(const void* q, const void* k, const void* v,
                                             const void* igk, const void* fgk,
                                             int* flag,
                                             unsigned short* qb, unsigned short* kb,
                                             unsigned short* vT,
                                             float* iparts, float* fparts) {
    __shared__ float x_lds[32][67];
    __shared__ int cnt;
    const int tid = threadIdx.x;

    if (tid == 0) cnt = 0;
    __syncthreads();
    {
        const unsigned short* qp = (const unsigned short*)q;
        int wild = 0;
        for (int i = tid; i < 2048; i += 256) {
            float x = b2f(qp[i]);
            float ax = fabsf(x);
            if (!(ax <= 100.0f) || (x != 0.0f && ax < 1e-6f)) wild++;
        }
        atomicAdd(&cnt, wild);
    }
    __syncthreads();
    const int bf = (cnt < 256) ? 1 : 0;
    if (blockIdx.x == 0 && blockIdx.y == 0 && tid == 0) *flag = bf;

    const int s0 = blockIdx.x * 32;
    const int z  = blockIdx.y;
    const int tz = z >> 1;              // 0=q, 1=k, 2=v
    const int dbase = (z & 1) * 1024;   // d-half
    const void* src = (tz == 0) ? q : (tz == 1) ? k : v;
    unsigned short* dst16 = (tz == 0) ? qb : kb;

    const int r  = tid >> 3, c0 = (tid & 7) * 8;   // stage mapping (32 rows x 64 cols)
    const int sl = tid >> 3, hh = tid & 7;         // gate mapping  (32 rows x 8 heads)
    float accI = 0.f, accF = 0.f;
    const unsigned short* ik16 = (const unsigned short*)igk;
    const unsigned short* fk16 = (const unsigned short*)fgk;
    const float* ik32 = (const float*)igk;
    const float* fk32 = (const float*)fgk;

    for (int ch = 0; ch < 16; ++ch) {
        const int d0 = dbase + ch * 64;
        float xv[8];
        const size_t base = (size_t)(s0 + r) * DMODEL + d0 + c0;
        if (bf) {
            const unsigned short* sp = (const unsigned short*)src;
            v8u a = *(const v8u*)(sp + base);
#pragma unroll
            for (int j = 0; j < 8; j++) xv[j] = b2f(a[j]);
        } else {
            const float* sp = (const float*)src;
            v4f a0 = *(const v4f*)(sp + base);
            v4f a1 = *(const v4f*)(sp + base + 4);
#pragma unroll
            for (int j = 0; j < 4; j++) { xv[j] = a0[j]; xv[4 + j] = a1[j]; }
        }
        __syncthreads();     // prior chunk fully consumed
#pragma unroll
        for (int j = 0; j < 8; j++) x_lds[r][c0 + j] = xv[j];
        if (tz < 2) {        // q/k: fp16 straight from registers
            v8u o;
#pragma unroll
            for (int j = 0; j < 8; j++) o[j] = f2h(xv[j]);
            *(v8u*)(dst16 + base) = o;
        }
        __syncthreads();
        // gate partial products (f32 inputs preserved)
        const int gd0 = tz * 2048 + d0;
        if (bf) {
#pragma unroll 8
            for (int j = 0; j < 64; j++) {
                float x = x_lds[sl][j];
                int wi = (gd0 + j) * NHEAD + hh;
                accI += x * b2f(ik16[wi]);
                accF += x * b2f(fk16[wi]);
            }
        } else {
#pragma unroll 8
            for (int j = 0; j < 64; j++) {
                float x = x_lds[sl][j];
                int wi = (gd0 + j) * NHEAD + hh;
                accI += x * ik32[wi];
                accF += x * fk32[wi];
            }
        }
        if (tz == 2) {       // v: transposed fp16 write
            const int dloc = tid >> 2, sc0 = (tid & 3) * 8;
            v8u o;
#pragma unroll
            for (int j = 0; j < 8; j++) o[j] = f2h(x_lds[sc0 + j][dloc]);
            const int dglob = d0 + dloc;
            const int head = dglob >> 8, dh = dglob & 255;
            *(v8u*)(vT + ((size_t)(head * DHEAD + dh)) * SEQ + s0 + sc0) = o;
        }
    }
    iparts[(size_t)z * NHEAD * SEQ + hh * SEQ + s0 + sl] = accI;
    fparts[(size_t)z * NHEAD * SEQ + hh * SEQ + s0 + sl] = accF;
}

// ---------------- per-head scans: cum(log_sigmoid(f)), a = i - cum, prefix-max
__global__ __launch_bounds__(256) void k_scan(const float* iparts, const float* fparts,
                                              const void* ib_, const void* fb_,
                                              const int* flag,
                                              float* a_g, float* amax_g, float* nfl_g) {
    __shared__ float sarr[256];
    int bf = *(volatile const int*)flag;
    int h = blockIdx.x, tid = threadIdx.x;
    float ib = bf ? b2f(((const unsigned short*)ib_)[h]) : ((const float*)ib_)[h];
    float fb = bf ? b2f(((const unsigned short*)fb_)[h]) : ((const float*)fb_)[h];
    int s0 = tid * 8;
    float lf[8], ip[8];
#pragma unroll
    for (int j = 0; j < 8; j++) {
        float fpv = fb, ipv = ib;
#pragma unroll
        for (int z = 0; z < 6; z++) {
            ipv += iparts[(size_t)z * NHEAD * SEQ + h * SEQ + s0 + j];
            fpv += fparts[(size_t)z * NHEAD * SEQ + h * SEQ + s0 + j];
        }
        lf[j] = fminf(fpv, 0.0f) - log1pf(__expf(-fabsf(fpv)));
        ip[j] = ipv;
    }
    float cs[8]; float t = 0.f;
#pragma unroll
    for (int j = 0; j < 8; j++) { t += lf[j]; cs[j] = t; }
    sarr[tid] = t; __syncthreads();
    for (int ofs = 1; ofs < 256; ofs <<= 1) {
        float val = sarr[tid];
        if (tid >= ofs) val += sarr[tid - ofs];
        __syncthreads(); sarr[tid] = val; __syncthreads();
    }
    float excl = (tid > 0) ? sarr[tid - 1] : 0.0f;
    float cum[8], av[8];
#pragma unroll
    for (int j = 0; j < 8; j++) { cum[j] = excl + cs[j]; av[j] = ip[j] - cum[j]; }
    float mx = av[0];
#pragma unroll
    for (int j = 1; j < 8; j++) mx = fmaxf(mx, av[j]);
    __syncthreads(); sarr[tid] = mx; __syncthreads();
    for (int ofs = 1; ofs < 256; ofs <<= 1) {
        float val = sarr[tid];
        if (tid >= ofs) val = fmaxf(val, sarr[tid - ofs]);
        __syncthreads(); sarr[tid] = val; __syncthreads();
    }
    float run = (tid > 0) ? sarr[tid - 1] : -3.0e38f;
#pragma unroll
    for (int j = 0; j < 8; j++) {
        run = fmaxf(run, av[j]);
        int s = s0 + j;
        a_g[h * SEQ + s]    = av[j];
        amax_g[h * SEQ + s] = run;
        float m = cum[j] + run;
        nfl_g[h * SEQ + s]  = __expf(fminf(fmaxf(-m, -60.f), 60.f));
    }
}

// --------------------------------------------------------------- main kernel
// Equal-work blocks: each of 64 blocks/head processes a fixed quota (33/32,
// interleaved so any adjacent pair sums to 65) of flattened (tile, js) units.
// The js-sum is order-independent (precomputed amax), so split tiles combine
// via f32 atomicAdd into h_buf/rs_buf; k_finish applies normalizer + LN.
__global__ __launch_bounds__(256) void k_main(const unsigned short* __restrict__ qb,
                                              const unsigned short* __restrict__ kb,
                                              const unsigned short* __restrict__ vT,
                                              const float* __restrict__ a_g,
                                              const float* __restrict__ amax_g,
                                              float* __restrict__ h_buf,
                                              float* __restrict__ rs_buf) {
    __shared__ __align__(16) unsigned short q_lds[32][264];
    __shared__ __align__(16) unsigned short k_lds[32][264];
    __shared__ __align__(16) unsigned short vT_lds[272][40];   // rows 256..271: ones/zeros
    __shared__ __align__(16) unsigned short P_lds[32][40];
    __shared__ __align__(16) unsigned short Plo_lds[32][40];
    __shared__ float a_s[32], amax_t[32];

    const int h   = blockIdx.x;
    const int y   = blockIdx.y;        // quota index within head, 0..63
    const int tid = threadIdx.x;
    const int lane = tid & 63;
    const int w   = tid >> 6;          // wave 0..3
    const int l15 = lane & 15;
    const int qd  = (lane >> 4) & 3;   // quad
    const int hd0 = h * DHEAD;

    // ---- quota: units [u, u+remaining) of this head's flattened triangle
    int u         = 65 * (y >> 1) + ((y & 1) ? 33 : 0);
    int remaining = (y & 1) ? 32 : 33;
    int tile = (int)((sqrtf(8.0f * (float)u + 1.0f) - 1.0f) * 0.5f);
    while ((tile + 1) * (tile + 2) / 2 <= u) ++tile;
    while (tile * (tile + 1) / 2 > u) --tile;
    int js = u - tile * (tile + 1) / 2;
    bool needQ = true;

    // ones/zeros rows for the normalizer trick
    for (int i = tid; i < 16 * 40; i += 256) {
        int r2 = i / 40, c2 = i % 40;
        vT_lds[256 + r2][c2] = (r2 == 0 && c2 < 32) ? (unsigned short)0x3C00 : (unsigned short)0;
    }

    const v4f vzero = {0.f, 0.f, 0.f, 0.f};
    v4f acc[2][4];
    v4f accN[2];
#pragma unroll
    for (int m = 0; m < 2; m++) {
        accN[m] = vzero;
#pragma unroll
        for (int n = 0; n < 4; n++) acc[m][n] = vzero;
    }

    const int mw = w >> 1, nw = w & 1;
    const int krow = tid >> 3, kc0 = (tid & 7) * 32;

    // staging registers (async-split: load early, ds_write late)
    v8u kr0, kr1, kr2, kr3, vr0, vr1, vr2, vr3;
    float areg = 0.f;
    {   // prefetch first unit
        const int s0 = js * 32;
        const unsigned short* ks = kb + (size_t)(s0 + krow) * DMODEL + hd0 + kc0;
        kr0 = *(const v8u*)(ks);      kr1 = *(const v8u*)(ks + 8);
        kr2 = *(const v8u*)(ks + 16); kr3 = *(const v8u*)(ks + 24);
        const unsigned short* vs = vT + (size_t)(hd0 + tid) * SEQ + s0;
        vr0 = *(const v8u*)(vs);      vr1 = *(const v8u*)(vs + 8);
        vr2 = *(const v8u*)(vs + 16); vr3 = *(const v8u*)(vs + 24);
        if (tid < 32) areg = a_g[h * SEQ + s0 + tid];
    }

    for (;;) {
        const int t0 = tile * 32;
        __syncthreads();   // previous unit's compute consumed LDS
        if (needQ) {       // new tile: stage q + per-row stabilizer
            const unsigned short* src = qb + (size_t)(t0 + krow) * DMODEL + hd0 + kc0;
#pragma unroll
            for (int i = 0; i < 4; i++)
                *(v8u*)&q_lds[krow][kc0 + i * 8] = *(const v8u*)(src + i * 8);
            if (tid < 32) amax_t[tid] = amax_g[h * SEQ + t0 + tid];
            needQ = false;
        }
        *(v8u*)&k_lds[krow][kc0]      = kr0;
        *(v8u*)&k_lds[krow][kc0 + 8]  = kr1;
        *(v8u*)&k_lds[krow][kc0 + 16] = kr2;
        *(v8u*)&k_lds[krow][kc0 + 24] = kr3;
        *(v8u*)&vT_lds[tid][0]  = vr0;
        *(v8u*)&vT_lds[tid][8]  = vr1;
        *(v8u*)&vT_lds[tid][16] = vr2;
        *(v8u*)&vT_lds[tid][24] = vr3;
        if (tid < 32) a_s[tid] = areg;
        __syncthreads();

        // QK^T: each wave computes one 16x16 tile of P (mw,nw)
        v4f c = vzero;
#pragma unroll
        for (int d0 = 0; d0 < 256; d0 += 32) {
            v8h a = *(const v8h*)&q_lds[mw * 16 + l15][d0 + qd * 8];
            v8h b = *(const v8h*)&k_lds[nw * 16 + l15][d0 + qd * 8];
            c = __builtin_amdgcn_mfma_f32_16x16x32_f16(a, b, c, 0, 0, 0);
        }
        // decay weights + causal mask; write P as fp16 hi + lo residual
        {
            const bool diag = (js == tile);
            const int col = nw * 16 + l15;
            const float av = a_s[col];
#pragma unroll
            for (int r = 0; r < 4; r++) {
                int row = mw * 16 + qd * 4 + r;
                float arg = fminf(av - amax_t[row], 0.0f);
                float val = c[r] * 0.0625f * __expf(arg);   // 1/sqrt(256) folded here
                if (diag && col > row) val = 0.0f;
                unsigned short hi = f2h(val);
                float lo = val - h2f(hi);
                P_lds[row][col]   = hi;
                Plo_lds[row][col] = f2h(lo);
            }
        }
        __syncthreads();

        // prefetch NEXT unit now; HBM/L2 latency hides under the PV phase below
        int ntile = tile, njs = js + 1; bool nq = false;
        if (njs > tile) { ntile = tile + 1; njs = 0; nq = true; }
        if (remaining > 1) {
            const int s0 = njs * 32;
            const unsigned short* ks = kb + (size_t)(s0 + krow) * DMODEL + hd0 + kc0;
            kr0 = *(const v8u*)(ks);      kr1 = *(const v8u*)(ks + 8);
            kr2 = *(const v8u*)(ks + 16); kr3 = *(const v8u*)(ks + 24);
            const unsigned short* vs = vT + (size_t)(hd0 + tid) * SEQ + s0;
            vr0 = *(const v8u*)(vs);      vr1 = *(const v8u*)(vs + 8);
            vr2 = *(const v8u*)(vs + 16); vr3 = *(const v8u*)(vs + 24);
            if (tid < 32) areg = a_g[h * SEQ + s0 + tid];
        }

        // P @ V (hi + lo): wave w owns output cols [w*64, w*64+64)
        v8h aH0 = *(const v8h*)&P_lds[l15][qd * 8];
        v8h aH1 = *(const v8h*)&P_lds[16 + l15][qd * 8];
        v8h aL0 = *(const v8h*)&Plo_lds[l15][qd * 8];
        v8h aL1 = *(const v8h*)&Plo_lds[16 + l15][qd * 8];
#pragma unroll
        for (int nn = 0; nn < 4; nn++) {
            v8h bV = *(const v8h*)&vT_lds[w * 64 + nn * 16 + l15][qd * 8];
            acc[0][nn] = __builtin_amdgcn_mfma_f32_16x16x32_f16(aH0, bV, acc[0][nn], 0, 0, 0);
            acc[0][nn] = __builtin_amdgcn_mfma_f32_16x16x32_f16(aL0, bV, acc[0][nn], 0, 0, 0);
            acc[1][nn] = __builtin_amdgcn_mfma_f32_16x16x32_f16(aH1, bV, acc[1][nn], 0, 0, 0);
            acc[1][nn] = __builtin_amdgcn_mfma_f32_16x16x32_f16(aL1, bV, acc[1][nn], 0, 0, 0);
        }
        if (w == 3) {   // ones-column trick: row normalizer (hi+lo)
            v8h bN = *(const v8h*)&vT_lds[256 + l15][qd * 8];
            accN[0] = __builtin_amdgcn_mfma_f32_16x16x32_f16(aH0, bN, accN[0], 0, 0, 0);
            accN[0] = __builtin_amdgcn_mfma_f32_16x16x32_f16(aL0, bN, accN[0], 0, 0, 0);
            accN[1] = __builtin_amdgcn_mfma_f32_16x16x32_f16(aH1, bN, accN[1], 0, 0, 0);
            accN[1] = __builtin_amdgcn_mfma_f32_16x16x32_f16(aL1, bN, accN[1], 0, 0, 0);
        }

        // flush at tile end or block end (raw partials; fire-and-forget atomics)
        if (js == tile || remaining == 1) {
#pragma unroll
            for (int m = 0; m < 2; m++)
#pragma unroll
                for (int r = 0; r < 4; r++) {
                    int row = t0 + m * 16 + qd * 4 + r;
#pragma unroll
                    for (int nn = 0; nn < 4; nn++) {
                        int col = hd0 + w * 64 + nn * 16 + l15;
                        atomicAdd(&h_buf[(size_t)row * DMODEL + col], acc[m][nn][r]);
                        acc[m][nn][r] = 0.f;
                    }
                    if (w == 3 && l15 == 0)
                        atomicAdd(&rs_buf[h * SEQ + row], accN[m][r]);
                    accN[m][r] = 0.f;
                }
        }
        if (--remaining == 0) break;
        tile = ntile; js = njs; needQ = nq;
    }
}

// ------------------------------------- finish: normalizer scale + per-head LN
__global__ __launch_bounds__(256) void k_finish(const float* __restrict__ h_buf,
                                                const float* __restrict__ rs_buf,
                                                const float* __restrict__ nfl_g,
                                                const void* __restrict__ ow,
                                                const int* flag, void* out) {
    const int wv = threadIdx.x >> 6, lane = threadIdx.x & 63;
    const int rid = blockIdx.x * 4 + wv;       // 0..16383
    const int s = rid >> 3, h = rid & 7;
    const int bf = *(volatile const int*)flag;
    float rs  = rs_buf[h * SEQ + s];
    float nfl = nfl_g[h * SEQ + s];
    float sc  = 1.0f / (fmaxf(fabsf(rs), nfl) + 1e-6f);
    size_t base = (size_t)s * DMODEL + h * DHEAD + lane * 4;
    v4f hv = *(const v4f*)(h_buf + base);
#pragma unroll
    for (int j = 0; j < 4; j++) hv[j] *= sc;
    float sm = hv[0] + hv[1] + hv[2] + hv[3];
    float sq = hv[0] * hv[0] + hv[1] * hv[1] + hv[2] * hv[2] + hv[3] * hv[3];
#pragma unroll
    for (int m = 1; m < 64; m <<= 1) {
        sm += __shfl_xor(sm, m, 64);
        sq += __shfl_xor(sq, m, 64);
    }
    float mean = sm * (1.0f / 256.0f);
    float var  = fmaxf(sq * (1.0f / 256.0f) - mean * mean, 0.0f);
    float rstd = rsqrtf(var + 1e-6f);
    int gi = h * DHEAD + lane * 4;
    float g0, g1, g2, g3;
    if (bf) {
        const unsigned short* gp = (const unsigned short*)ow;
        g0 = b2f(gp[gi]); g1 = b2f(gp[gi + 1]); g2 = b2f(gp[gi + 2]); g3 = b2f(gp[gi + 3]);
    } else {
        const float* gp = (const float*)ow;
        g0 = gp[gi]; g1 = gp[gi + 1]; g2 = gp[gi + 2]; g3 = gp[gi + 3];
    }
    float gv[4] = {g0, g1, g2, g3};
    if (bf) {
        unsigned short* o = (unsigned short*)out + base;
#pragma unroll
        for (int j = 0; j < 4; j++) o[j] = f2b((hv[j] - mean) * rstd * gv[j]);
    } else {
        float* o = (float*)out + base;
#pragma unroll
        for (int j = 0; j < 4; j++) o[j] = (hv[j] - mean) * rstd * gv[j];
    }
}

// ---------------------------------------------------------------------- host
extern "C" void kernel_launch(void* const* d_in, const int* in_sizes, int n_in,
                              void* d_out, int out_size, void* d_ws, size_t ws_size,
                              hipStream_t stream) {
    const void* q   = d_in[0];
    const void* k   = d_in[1];
    const void* v   = d_in[2];
    const void* igk = d_in[3];
    const void* igb = d_in[4];
    const void* fgk = d_in[5];
    const void* fgb = d_in[6];
    const void* ow  = d_in[7];

    char* ws = (char*)d_ws;
    int*   flag   = (int*)(ws + 0);
    float* iparts = (float*)(ws + 1024);                       // 6*8*2048 f32 = 384 KiB
    float* fparts = iparts + 6 * NHEAD * SEQ;                  // 384 KiB
    float* a_g    = fparts + 6 * NHEAD * SEQ;
    float* amax_g = a_g + NHEAD * SEQ;
    float* nfl_g  = amax_g + NHEAD * SEQ;
    unsigned short* qb = (unsigned short*)(nfl_g + NHEAD * SEQ);
    unsigned short* kb = qb + (size_t)SEQ * DMODEL;
    unsigned short* vT = kb + (size_t)SEQ * DMODEL;
    float* rs_buf = (float*)(vT + (size_t)SEQ * DMODEL);
    float* h_buf  = rs_buf + NHEAD * SEQ;                      // contiguous with rs_buf

    // 5 graph nodes total
    hipMemsetAsync(rs_buf, 0, (size_t)NHEAD * SEQ * 4 + (size_t)SEQ * DMODEL * 4, stream);
    k_pre<<<dim3(64, 6), 256, 0, stream>>>(q, k, v, igk, fgk, flag, qb, kb, vT, iparts, fparts);
    k_scan<<<8, 256, 0, stream>>>(iparts, fparts, igb, fgb, flag, a_g, amax_g, nfl_g);
    k_main<<<dim3(8, 64), 256, 0, stream>>>(qb, kb, vT, a_g, amax_g, h_buf, rs_buf);
    k_finish<<<4096, 256, 0, stream>>>(h_buf, rs_buf, nfl_g, ow, flag, d_out);
}